// Round 8
// baseline (160.608 us; speedup 1.0000x reference)
//
#include <hip/hip_runtime.h>
#include <hip/hip_bf16.h>
#include <math.h>

// Problem constants (B=2, S=2048, C=1024, H=16, D=64, Cv=1024)
#define B_    2
#define S_    2048
#define C_    1024
#define H_    16
#define D_    64
#define TWO_C 2048
#define CV    1024
#define K_    1024
#define N_ALL 3072   // Wqk (2048) ++ Wv (1024)

typedef float  floatx4 __attribute__((ext_vector_type(4)));
typedef short  shortx8 __attribute__((ext_vector_type(8)));
typedef short  shortx4 __attribute__((ext_vector_type(4)));

__device__ __forceinline__ ushort f2bf(float f) {
  unsigned u = __builtin_bit_cast(unsigned, f);
  u += 0x7fff + ((u >> 16) & 1);   // RNE
  return (ushort)(u >> 16);
}

// async global->LDS, 16B per lane; LDS dst = wave-uniform base + lane*16
__device__ __forceinline__ void gl2lds16(const ushort* g, ushort* l) {
  __builtin_amdgcn_global_load_lds(
      (const __attribute__((address_space(1))) unsigned int*)(const void*)g,
      (__attribute__((address_space(3))) unsigned int*)(void*)l, 16, 0, 0);
}

// ---------------- prep v2: 1024 fat blocks ---------------------------------
//   [0, 256):    x fp32 -> xbf, grid-stride float4 (16 iters/thread)
//   [256, 768):  Wqk [1024][2048] -> wtbf rows [N][K], 64x64 tiles
//   [768, 1024): Wv  [1024][1024] -> wtbf[2048..) rows, 64x64 tiles
__global__ __launch_bounds__(256) void prep_kernel(
    const float* __restrict__ x, const float* __restrict__ Wqk,
    const float* __restrict__ Wv, ushort* __restrict__ xbf,
    ushort* __restrict__ wtbf) {
  const int blk = blockIdx.x;
  if (blk < 256) {
    const int stride = 256 * 256;
    for (int i = blk * 256 + threadIdx.x; i < (B_ * S_ * C_) / 4; i += stride) {
      float4 v = *(const float4*)(x + (size_t)i * 4);
      shortx4 s;
      s[0] = (short)f2bf(v.x); s[1] = (short)f2bf(v.y);
      s[2] = (short)f2bf(v.z); s[3] = (short)f2bf(v.w);
      *(shortx4*)(xbf + (size_t)i * 4) = s;
    }
    return;
  }
  // 64x64 transpose tile: tile[n][k] (bf16), read coalesced, write coalesced
  __shared__ ushort tile[64][65];
  int idx = blk - 256;
  const float* W; ushort* WT; int N;
  if (idx < 512) { W = Wqk; WT = wtbf; N = TWO_C; }
  else { idx -= 512; W = Wv; WT = wtbf + (size_t)TWO_C * K_; N = CV; }
  const int nb = N / 64;
  const int n0 = (idx % nb) * 64, k0 = (idx / nb) * 64;
  const int tc = threadIdx.x & 63, tr = threadIdx.x >> 6;   // tr 0..3
#pragma unroll
  for (int i = 0; i < 64; i += 4)
    tile[tc][tr + i] = f2bf(W[(size_t)(k0 + tr + i) * N + n0 + tc]);
  __syncthreads();
  const int n = threadIdx.x >> 2, ch = threadIdx.x & 3;   // row n, 16-col chunk
  shortx8 s0, s1;
#pragma unroll
  for (int j = 0; j < 8; j++) { s0[j] = tile[n][ch * 16 + j]; s1[j] = tile[n][ch * 16 + 8 + j]; }
  ushort* dst = WT + (size_t)(n0 + n) * K_ + k0 + ch * 16;
  *(shortx8*)(dst) = s0;
  *(shortx8*)(dst + 8) = s1;
}

// ---------------- fused projection GEMM (unchanged R7: known-good 50us) ----
__global__ __launch_bounds__(256) void gemm_mfma(
    const ushort* __restrict__ A, const ushort* __restrict__ BT,
    const float* __restrict__ bqk, const float* __restrict__ bv,
    ushort* __restrict__ qkout, ushort* __restrict__ vtout) {
  __shared__ __align__(16) ushort As[128 * 64];   // 16 KB
  __shared__ __align__(16) ushort Bs[128 * 64];   // 16 KB

  const int tx = threadIdx.x;
  const int w = tx >> 6;
  const int lane = tx & 63;
  const int lq = lane & 15;
  const int quad = lane >> 4;
  const int row0 = blockIdx.x * 128;   // row fastest (XCD round-robin shares B)
  const int col0 = blockIdx.y * 128;
  const int wm = (w & 1) * 64;
  const int wn = (w >> 1) * 64;

  const int srow = lane >> 3;
  const int schunk = ((lane & 7) ^ srow) * 8;
  const ushort* ag = A  + (size_t)(row0 + srow) * K_ + schunk;
  const ushort* bg = BT + (size_t)(col0 + srow) * K_ + schunk;

  floatx4 acc[4][4];
#pragma unroll
  for (int i = 0; i < 4; i++)
#pragma unroll
    for (int j = 0; j < 4; j++) acc[i][j] = (floatx4){0.f, 0.f, 0.f, 0.f};

  for (int k0 = 0; k0 < K_; k0 += 64) {
#pragma unroll
    for (int j = 0; j < 4; j++) {
      const int g = w * 4 + j;
      gl2lds16(ag + (size_t)(g * 8) * K_ + k0, As + g * 512);
      gl2lds16(bg + (size_t)(g * 8) * K_ + k0, Bs + g * 512);
    }
    __syncthreads();

#pragma unroll
    for (int kh = 0; kh < 2; kh++) {
      const int co = ((kh * 4 + quad) ^ (lq & 7)) * 8;
      shortx8 af[4], bf[4];
#pragma unroll
      for (int mi = 0; mi < 4; mi++)
        af[mi] = *(const shortx8*)(As + (wm + mi * 16 + lq) * 64 + co);
#pragma unroll
      for (int ni = 0; ni < 4; ni++)
        bf[ni] = *(const shortx8*)(Bs + (wn + ni * 16 + lq) * 64 + co);
#pragma unroll
      for (int mi = 0; mi < 4; mi++)
#pragma unroll
        for (int ni = 0; ni < 4; ni++)
          acc[mi][ni] = __builtin_amdgcn_mfma_f32_16x16x32_bf16(
              af[mi], bf[ni], acc[mi][ni], 0, 0, 0);
    }
    __syncthreads();
  }

  if (col0 < TWO_C) {
#pragma unroll
    for (int mi = 0; mi < 4; mi++) {
      const int m0 = row0 + wm + mi * 16 + quad * 4;
#pragma unroll
      for (int ni = 0; ni < 4; ni++) {
        const int n = col0 + wn + ni * 16 + lq;
        const float bs = bqk[n];
        const float sc = (n < C_) ? 0.125f : 1.0f;
#pragma unroll
        for (int r = 0; r < 4; r++)
          qkout[(size_t)(m0 + r) * TWO_C + n] = f2bf((acc[mi][ni][r] + bs) * sc);
      }
    }
  } else {
#pragma unroll
    for (int mi = 0; mi < 4; mi++) {
      const int m0 = row0 + wm + mi * 16 + quad * 4;
      const int b = m0 >> 11, s = m0 & (S_ - 1);
#pragma unroll
      for (int ni = 0; ni < 4; ni++) {
        const int n = col0 - TWO_C + wn + ni * 16 + lq;
        const float bs = bv[n];
        shortx4 st;
#pragma unroll
        for (int r = 0; r < 4; r++) st[r] = (short)f2bf(acc[mi][ni][r] + bs);
        *(shortx4*)(vtout + ((size_t)((b << 4) | (n >> 6)) * 64 + (n & 63)) * S_ + s) = st;
      }
    }
  }
}

// ---------------- Flash attention v3: double-buffered K/V, 1 barrier/iter --
// LDS = 2*(8KB K) + 2*(8KB V) + 8KB P = 40960 B exactly -> 4 blocks/CU.
// Loop: barrier (drains buf's DMA via vmcnt) -> issue DMA(t+1 -> buf^1)
//       -> compute(t on buf). DMA latency overlaps compute.
__global__ __launch_bounds__(256, 4) void flash_attn(
    const ushort* __restrict__ qk, const ushort* __restrict__ vt,
    float* __restrict__ out) {
  __shared__ __align__(16) ushort Ks[2][64 * 64];   // 16 KB
  __shared__ __align__(16) ushort Vs[2][64 * 64];   // 16 KB
  __shared__ __align__(16) ushort Ps[4][16 * 64];   // 8 KB, XOR-octet swizzled

  const int w = threadIdx.x >> 6;
  const int lane = threadIdx.x & 63;
  const int lq = lane & 15;
  const int quad = lane >> 4;

  const int bh = blockIdx.x & 31;
  const int qtile = 31 - (blockIdx.x >> 5);  // heavy tiles first
  const int b = bh >> 4, h = bh & 15;
  const int q0 = qtile * 64;
  const int qloc = w * 16 + lq;
  const int qg = q0 + qloc;

  const ushort* qbase = qk + (size_t)(b * S_ + qg) * TWO_C + h * D_;
  const shortx8 qf0 = *(const shortx8*)(qbase + quad * 8);
  const shortx8 qf1 = *(const shortx8*)(qbase + 32 + quad * 8);

  const ushort* kbase = qk + (size_t)b * S_ * TWO_C + C_ + h * D_;
  const ushort* vbase = vt + (size_t)(b * H_ + h) * D_ * S_;

  const int kk = lane >> 3, oo = lane & 7;
  const int oswz = (oo ^ kk) * 8;
  const ushort* ksrc = kbase + (size_t)(w * 16 + kk) * TWO_C + oswz;
  const ushort* vsrc = vbase + (size_t)(w * 16 + kk) * S_ + oswz;

  const int xo0 = ((0 * 4 + quad) ^ (lq & 7)) * 8;
  const int xo1 = ((1 * 4 + quad) ^ (lq & 7)) * 8;

  // P swizzle: row stride 64; col c -> octet (c>>3) ^ (lq&7), pos c&7
  const int pw0 = lq * 64 + (((quad >> 1) ^ (lq & 7)) << 3) + (quad & 1) * 4;       // s=0 base (c=quad*4)
  const int pr0 = lq * 64 + ((quad ^ (lq & 7)) << 3);          // read cols quad*8
  const int pr1 = lq * 64 + (((4 + quad) ^ (lq & 7)) << 3);    // read cols 32+quad*8

  floatx4 o[4];
#pragma unroll
  for (int i = 0; i < 4; i++) o[i] = (floatx4){0.f, 0.f, 0.f, 0.f};
  float l = 0.f;
  ushort* Pw = Ps[w];

  const int nkt = qtile + 1;

  // preload tile 0 into buffer 0
  {
    gl2lds16(ksrc, Ks[0] + (2 * w) * 512);
    gl2lds16(ksrc + 8 * TWO_C, Ks[0] + (2 * w + 1) * 512);
    gl2lds16(vsrc, Vs[0] + (2 * w) * 512);
    gl2lds16(vsrc + 8 * S_, Vs[0] + (2 * w + 1) * 512);
  }

  for (int t = 0; t < nkt; t++) {
    const int buf = t & 1;
    __syncthreads();   // drains vmcnt: buf's DMA complete; buf^1 free

    if (t + 1 < nkt) {
      const size_t k1 = (size_t)(t + 1) * 64;
      ushort* kd = Ks[buf ^ 1];
      ushort* vd = Vs[buf ^ 1];
      gl2lds16(ksrc + k1 * TWO_C,             kd + (2 * w) * 512);
      gl2lds16(ksrc + k1 * TWO_C + 8 * TWO_C, kd + (2 * w + 1) * 512);
      gl2lds16(vsrc + k1,                     vd + (2 * w) * 512);
      gl2lds16(vsrc + k1 + 8 * S_,            vd + (2 * w + 1) * 512);
    }

    const ushort* Kb = Ks[buf];
    const ushort* Vb = Vs[buf];

    floatx4 sa[4];
#pragma unroll
    for (int s = 0; s < 4; s++) {
      const int rb = (s * 16 + lq) * 64;
      const shortx8 kf0 = *(const shortx8*)(Kb + rb + xo0);
      const shortx8 kf1 = *(const shortx8*)(Kb + rb + xo1);
      floatx4 a = {0.f, 0.f, 0.f, 0.f};
      a = __builtin_amdgcn_mfma_f32_16x16x32_bf16(kf0, qf0, a, 0, 0, 0);
      a = __builtin_amdgcn_mfma_f32_16x16x32_bf16(kf1, qf1, a, 0, 0, 0);
      sa[s] = a;
    }

    if (t == qtile) {
#pragma unroll
      for (int s = 0; s < 4; s++)
#pragma unroll
        for (int r = 0; r < 4; r++)
          if (s * 16 + quad * 4 + r > qloc) sa[s][r] = -1e30f;
    }

    float psum = 0.f;
#pragma unroll
    for (int s = 0; s < 4; s++) {
      shortx4 pw;
#pragma unroll
      for (int r = 0; r < 4; r++) {
        float p = __expf(sa[s][r]);
        psum += p;
        pw[r] = (short)f2bf(p);
      }
      // col base c = s*16 + quad*4 -> octet (s*2 + (quad>>1)) ^ (lq&7)
      *(shortx4*)(Pw + (pw0 ^ ((s * 2) << 3))) = pw;
    }
    l += psum;
    __asm__ __volatile__("s_waitcnt lgkmcnt(0)" ::: "memory");

    const shortx8 pf0 = *(const shortx8*)(Pw + pr0);
    const shortx8 pf1 = *(const shortx8*)(Pw + pr1);

#pragma unroll
    for (int ds = 0; ds < 4; ds++) {
      const int rb = (ds * 16 + lq) * 64;
      const shortx8 vf0 = *(const shortx8*)(Vb + rb + xo0);
      const shortx8 vf1 = *(const shortx8*)(Vb + rb + xo1);
      o[ds] = __builtin_amdgcn_mfma_f32_16x16x32_bf16(vf0, pf0, o[ds], 0, 0, 0);
      o[ds] = __builtin_amdgcn_mfma_f32_16x16x32_bf16(vf1, pf1, o[ds], 0, 0, 0);
    }
  }

  l += __shfl_xor(l, 16, 64);
  l += __shfl_xor(l, 32, 64);
  const float inv = 1.0f / l;

  float* op = out + (size_t)(b * S_ + qg) * CV + h * D_ + quad * 4;
  *(floatx4*)(op + 0)  = o[0] * inv;
  *(floatx4*)(op + 16) = o[1] * inv;
  *(floatx4*)(op + 32) = o[2] * inv;
  *(floatx4*)(op + 48) = o[3] * inv;
}

extern "C" void kernel_launch(void* const* d_in, const int* in_sizes, int n_in,
                              void* d_out, int out_size, void* d_ws, size_t ws_size,
                              hipStream_t stream) {
  const float* x   = (const float*)d_in[0];
  const float* Wqk = (const float*)d_in[1];
  const float* bqk = (const float*)d_in[2];
  const float* Wv  = (const float*)d_in[3];
  const float* bv  = (const float*)d_in[4];
  float* out = (float*)d_out;

  // Workspace (ushorts): qk [4096][2048] | V^T [2048][2048] | xbf [4096][1024]
  //                      | wtbf [3072][1024]   => ~39.8 MB total
  ushort* qkbf = (ushort*)d_ws;
  ushort* vtbf = qkbf + (size_t)(B_ * S_) * TWO_C;
  ushort* xbf  = vtbf + (size_t)TWO_C * S_;
  ushort* wtbf = xbf  + (size_t)(B_ * S_) * K_;

  dim3 blk(256);
  prep_kernel<<<dim3(1024), blk, 0, stream>>>(x, Wqk, Wv, xbf, wtbf);
  gemm_mfma<<<dim3((B_ * S_) / 128, N_ALL / 128), blk, 0, stream>>>(
      xbf, wtbf, bqk, bv, qkbf, vtbf);
  flash_attn<<<dim3(32 * 32), blk, 0, stream>>>(qkbf, vtbf, out);
}